// Round 7
// baseline (73.767 us; speedup 1.0000x reference)
//
#include <hip/hip_runtime.h>
#include <cstdint>
#include <cstddef>
#include <math.h>

#define B 16
#define S 200
#define D 128
#define VOCAB 100000
#define V4 (VOCAB / 4)                 // 25000 float4 columns
#define SCH 8
#define NBLK ((V4 + 63) / 64)          // 391

// K1: attention scores: per block = one (b, chunk of 8 s). 128 threads (one per e-dim).
__global__ __launch_bounds__(128) void k_scores(
    const float* __restrict__ x,
    const float* __restrict__ Wq, const float* __restrict__ bq,
    const float* __restrict__ Wk, const float* __restrict__ bk,
    const float* __restrict__ Wv, const float* __restrict__ bv,
    float* __restrict__ scores)
{
  const int b  = blockIdx.x / (S / SCH);
  const int s0 = (blockIdx.x % (S / SCH)) * SCH;
  const int e  = threadIdx.x;

  __shared__ float lx[SCH][D];
  __shared__ float l0[D];
  __shared__ float sred[2][SCH];

  l0[e] = x[(size_t)b * S * D + e];
  #pragma unroll
  for (int i = 0; i < SCH; i++) lx[i][e] = x[((size_t)b * S + s0 + i) * D + e];
  __syncthreads();

  float q[SCH];
  const float bqe = bq[e];
  #pragma unroll
  for (int i = 0; i < SCH; i++) q[i] = bqe;
  float kk = bk[e];

  for (int d = 0; d < D; d++) {
    const float wq = Wq[d * D + e];
    const float wk = Wk[d * D + e];
    const float x0 = l0[d];
    kk += x0 * wk;
    #pragma unroll
    for (int i = 0; i < SCH; i++) q[i] += lx[i][d] * wq;
  }

  const float wv  = Wv[e];
  const float bv0 = bv[0];
  #pragma unroll
  for (int i = 0; i < SCH; i++) {
    float val = tanhf(q[i] + kk) * wv;
    #pragma unroll
    for (int off = 32; off > 0; off >>= 1) val += __shfl_down(val, off, 64);
    if ((e & 63) == 0) sred[e >> 6][i] = val;
  }
  __syncthreads();
  if (e < SCH) scores[b * S + s0 + e] = sred[0][e] + sred[1][e] + bv0;
}

// K2: softmax over S + c_s; 512 threads: 4 s-splits x 128 d.
// Writes cvec[dd*16 + b], dd 0..255 (h_t | c_s).
__global__ __launch_bounds__(512) void k_csum(
    const float* __restrict__ x, const float* __restrict__ scores,
    float* __restrict__ cvec)
{
  const int b = blockIdx.x;
  const int t = threadIdx.x;
  __shared__ float pr[S];
  __shared__ float redm[9];
  __shared__ float reds[9];
  __shared__ float cpart[3][D];

  float v = (t < S) ? scores[b * S + t] : -INFINITY;
  float m = v;
  #pragma unroll
  for (int off = 32; off > 0; off >>= 1) m = fmaxf(m, __shfl_down(m, off, 64));
  if ((t & 63) == 0) redm[t >> 6] = m;
  __syncthreads();
  if (t == 0) {
    float mm = redm[0];
    #pragma unroll
    for (int i = 1; i < 8; i++) mm = fmaxf(mm, redm[i]);
    redm[8] = mm;
  }
  __syncthreads();
  const float mx = redm[8];

  float e = (t < S) ? expf(v - mx) : 0.f;
  float s = e;
  #pragma unroll
  for (int off = 32; off > 0; off >>= 1) s += __shfl_down(s, off, 64);
  if ((t & 63) == 0) reds[t >> 6] = s;
  __syncthreads();
  if (t == 0) {
    float ss = 0.f;
    #pragma unroll
    for (int i = 0; i < 8; i++) ss += reds[i];
    reds[8] = ss;
  }
  __syncthreads();
  const float inv = 1.0f / reds[8];
  if (t < S) pr[t] = e * inv;
  __syncthreads();

  const int d = t & 127;
  const int sq = t >> 7;
  float acc = 0.f;
  const float* xb = x + ((size_t)b * S + sq * 50) * D + d;
  #pragma unroll 5
  for (int s2 = 0; s2 < 50; s2++) acc += pr[sq * 50 + s2] * xb[s2 * D];
  if (sq) cpart[sq - 1][d] = acc;
  __syncthreads();
  if (sq == 0) {
    cvec[d * B + b]       = x[(size_t)b * S * D + d];
    cvec[(D + d) * B + b] = acc + cpart[0][d] + cpart[1][d] + cpart[2][d];
  }
}

// K3: fused gemv + bias + exp + per-block partial sums.
// Block: 256 v (float4 per lane), d-split 4 across waves (64 d each).
// W loads: inline-asm global_load_dwordx4, 8-16 in flight, counted vmcnt
// waits + sched_barrier(0). __launch_bounds__(256, 2): grant 256 VGPRs so
// the allocator cannot re-roll/spill the pipeline (R2/R3 showed VGPR=20/40
// -> compiler was squeezing for occupancy, serializing every load).
__global__ __launch_bounds__(256, 2) void k_gemv(
    const float* __restrict__ cvec, const float* __restrict__ Wec,
    const float* __restrict__ bec, float* __restrict__ out,
    float* __restrict__ partial)
{
  __shared__ float2 red[4][64][17];    // 34816 B

  const int t    = threadIdx.x;
  const int lane = t & 63;
  const int dq   = __builtin_amdgcn_readfirstlane(t >> 6);  // d-quarter

  const int v4    = blockIdx.x * 64 + lane;   // float4 column index
  const bool valid = (v4 < V4);
  const int v4c   = valid ? v4 : (V4 - 1);

  const float4* wp = (const float4*)Wec + (size_t)(dq * 64) * V4 + v4c;
  const float*  cp = cvec + dq * 64 * 16;

  float4 acc[16];
  #pragma unroll
  for (int i = 0; i < 16; i++) acc[i] = make_float4(0.f, 0.f, 0.f, 0.f);

  float4 wa[8], wb[8];

#define ISSUE(buf, c0)                                                    \
  { _Pragma("unroll")                                                     \
    for (int j = 0; j < 8; j++)                                           \
      asm volatile("global_load_dwordx4 %0, %1, off"                      \
                   : "=&v"(buf[j])                                        \
                   : "v"(wp + (size_t)((c0) * 8 + j) * V4)); }

#define WAITC(n)                                                          \
  { asm volatile("s_waitcnt vmcnt(" #n ")" ::: "memory");                 \
    __builtin_amdgcn_sched_barrier(0); }

#define COMP(buf, c0)                                                     \
  { _Pragma("unroll")                                                     \
    for (int j = 0; j < 8; j++) {                                         \
      const float* cj = cp + ((c0) * 8 + j) * 16;                         \
      const float4 w = buf[j];                                            \
      _Pragma("unroll")                                                   \
      for (int bb = 0; bb < 16; bb++) {                                   \
        const float cc = cj[bb];                                          \
        acc[bb].x = fmaf(w.x, cc, acc[bb].x);                             \
        acc[bb].y = fmaf(w.y, cc, acc[bb].y);                             \
        acc[bb].z = fmaf(w.z, cc, acc[bb].z);                             \
        acc[bb].w = fmaf(w.w, cc, acc[bb].w);                             \
      } } }

  ISSUE(wa, 0)
  ISSUE(wb, 1)
  WAITC(8)  COMP(wa, 0)  ISSUE(wa, 2)
  WAITC(8)  COMP(wb, 1)  ISSUE(wb, 3)
  WAITC(8)  COMP(wa, 2)  ISSUE(wa, 4)
  WAITC(8)  COMP(wb, 3)  ISSUE(wb, 5)
  WAITC(8)  COMP(wa, 4)  ISSUE(wa, 6)
  WAITC(8)  COMP(wb, 5)  ISSUE(wb, 7)
  WAITC(8)  COMP(wa, 6)
  WAITC(0)  COMP(wb, 7)

#undef ISSUE
#undef WAITC
#undef COMP

  const float4 be4 = ((const float4*)bec)[v4c];
  float psum[4] = {0.f, 0.f, 0.f, 0.f};

  // Pass A: v-offsets 0,1 (acc .xy)
  #pragma unroll
  for (int bb = 0; bb < 16; bb++)
    red[dq][lane][bb] = make_float2(acc[bb].x, acc[bb].y);
  __syncthreads();
  #pragma unroll
  for (int i = 0; i < 4; i++) {
    const int bb = dq * 4 + i;
    const float2 r0 = red[0][lane][bb], r1 = red[1][lane][bb];
    const float2 r2 = red[2][lane][bb], r3 = red[3][lane][bb];
    const float sx = r0.x + r1.x + r2.x + r3.x;
    const float sy = r0.y + r1.y + r2.y + r3.y;
    const float e0 = valid ? __expf(sx + be4.x) : 0.f;
    const float e1 = valid ? __expf(sy + be4.y) : 0.f;
    if (valid)
      *(float2*)&out[(size_t)bb * VOCAB + (size_t)v4 * 4] = make_float2(e0, e1);
    psum[i] += e0 + e1;
  }
  __syncthreads();

  // Pass B: v-offsets 2,3 (acc .zw)
  #pragma unroll
  for (int bb = 0; bb < 16; bb++)
    red[dq][lane][bb] = make_float2(acc[bb].z, acc[bb].w);
  __syncthreads();
  #pragma unroll
  for (int i = 0; i < 4; i++) {
    const int bb = dq * 4 + i;
    const float2 r0 = red[0][lane][bb], r1 = red[1][lane][bb];
    const float2 r2 = red[2][lane][bb], r3 = red[3][lane][bb];
    const float sz = r0.x + r1.x + r2.x + r3.x;
    const float sw = r0.y + r1.y + r2.y + r3.y;
    const float e2 = valid ? __expf(sz + be4.z) : 0.f;
    const float e3 = valid ? __expf(sw + be4.w) : 0.f;
    if (valid)
      *(float2*)&out[(size_t)bb * VOCAB + (size_t)v4 * 4 + 2] = make_float2(e2, e3);
    psum[i] += e2 + e3;
  }

  #pragma unroll
  for (int i = 0; i < 4; i++) {
    float s = psum[i];
    #pragma unroll
    for (int off = 32; off > 0; off >>= 1) s += __shfl_down(s, off, 64);
    if (lane == 0) partial[blockIdx.x * 16 + dq * 4 + i] = s;
  }
}

// K4: single block: zero masked entries (duplicate-safe via atomicExch),
// subtract their exps from the sums, produce inv[b].
__global__ __launch_bounds__(256) void k_fix_inv(
    const int* __restrict__ ids, float* __restrict__ out,
    const float* __restrict__ partial, float* __restrict__ inv)
{
  const int t = threadIdx.x;
  __shared__ float corr[16];
  __shared__ float sred[256];

  if (t < 16) corr[t] = 0.f;
  __syncthreads();

  for (int i = t; i < B * S; i += 256) {
    const int id = ids[i];
    if (id > 1) {
      const int b = i / S;
      const float old = atomicExch(&out[(size_t)b * VOCAB + id], 0.f);
      atomicAdd(&corr[b], -old);
    }
  }

  float s = 0.f;
  #pragma unroll 4
  for (int j = (t >> 4); j < NBLK; j += 16) s += partial[j * 16 + (t & 15)];
  sred[t] = s;
  __syncthreads();

  if (t < 16) {
    float tot = 0.f;
    #pragma unroll
    for (int c = 0; c < 16; c++) tot += sred[c * 16 + t];
    inv[t] = 1.0f / (tot + corr[t]);
  }
}

// K5: scale in place, float4.
__global__ __launch_bounds__(256) void k_norm(float* __restrict__ out,
                                              const float* __restrict__ inv)
{
  const int b  = blockIdx.y;
  const int i4 = blockIdx.x * 256 + threadIdx.x;
  const float iv = inv[b];
  if (i4 < V4) {
    float4* p = (float4*)out + (size_t)b * V4 + i4;
    float4 q = *p;
    q.x *= iv; q.y *= iv; q.z *= iv; q.w *= iv;
    *p = q;
  }
}

extern "C" void kernel_launch(void* const* d_in, const int* in_sizes, int n_in,
                              void* d_out, int out_size, void* d_ws, size_t ws_size,
                              hipStream_t stream)
{
  const float* x   = (const float*)d_in[0];
  const int*   ids = (const int*)d_in[1];
  const float* Wq  = (const float*)d_in[2];
  const float* bq  = (const float*)d_in[3];
  const float* Wk  = (const float*)d_in[4];
  const float* bk  = (const float*)d_in[5];
  const float* Wv  = (const float*)d_in[6];
  const float* bv  = (const float*)d_in[7];
  const float* Wec = (const float*)d_in[8];
  const float* bec = (const float*)d_in[9];
  float* out = (float*)d_out;
  float* ws  = (float*)d_ws;

  float* scores  = ws;            // 3200
  float* cvec    = ws + 3200;     // 4096  ([256][16])
  float* partial = ws + 7296;     // NBLK*16 = 6256
  float* inv     = ws + 13552;    // 16

  k_scores <<<dim3(B * (S / SCH)), dim3(128), 0, stream>>>(x, Wq, bq, Wk, bk, Wv, bv, scores);
  k_csum   <<<dim3(B),             dim3(512), 0, stream>>>(x, scores, cvec);
  k_gemv   <<<dim3(NBLK),          dim3(256), 0, stream>>>(cvec, Wec, bec, out, partial);
  k_fix_inv<<<dim3(1),             dim3(256), 0, stream>>>(ids, out, partial, inv);
  k_norm   <<<dim3((V4 + 255) / 256, B), dim3(256), 0, stream>>>(out, inv);
}

// Round 9
// 66.647 us; speedup vs baseline: 1.1068x; 1.1068x over previous
//
#include <hip/hip_runtime.h>
#include <cstdint>
#include <cstddef>
#include <math.h>

#define B 16
#define S 200
#define D 128
#define VOCAB 100000
#define V4 (VOCAB / 4)                 // 25000 float4 columns
#define SCH 8
#define VTILE 256                      // vocab words per block
#define NBLK ((VOCAB + VTILE - 1) / VTILE)   // 391

// K1: attention scores: per block = one (b, chunk of 8 s). 128 threads (one per e-dim).
__global__ __launch_bounds__(128) void k_scores(
    const float* __restrict__ x,
    const float* __restrict__ Wq, const float* __restrict__ bq,
    const float* __restrict__ Wk, const float* __restrict__ bk,
    const float* __restrict__ Wv, const float* __restrict__ bv,
    float* __restrict__ scores)
{
  const int b  = blockIdx.x / (S / SCH);
  const int s0 = (blockIdx.x % (S / SCH)) * SCH;
  const int e  = threadIdx.x;

  __shared__ float lx[SCH][D];
  __shared__ float l0[D];
  __shared__ float sred[2][SCH];

  l0[e] = x[(size_t)b * S * D + e];
  #pragma unroll
  for (int i = 0; i < SCH; i++) lx[i][e] = x[((size_t)b * S + s0 + i) * D + e];
  __syncthreads();

  float q[SCH];
  const float bqe = bq[e];
  #pragma unroll
  for (int i = 0; i < SCH; i++) q[i] = bqe;
  float kk = bk[e];

  for (int d = 0; d < D; d++) {
    const float wq = Wq[d * D + e];
    const float wk = Wk[d * D + e];
    const float x0 = l0[d];
    kk += x0 * wk;
    #pragma unroll
    for (int i = 0; i < SCH; i++) q[i] += lx[i][d] * wq;
  }

  const float wv  = Wv[e];
  const float bv0 = bv[0];
  #pragma unroll
  for (int i = 0; i < SCH; i++) {
    float val = tanhf(q[i] + kk) * wv;
    #pragma unroll
    for (int off = 32; off > 0; off >>= 1) val += __shfl_down(val, off, 64);
    if ((e & 63) == 0) sred[e >> 6][i] = val;
  }
  __syncthreads();
  if (e < SCH) scores[b * S + s0 + e] = sred[0][e] + sred[1][e] + bv0;
}

// K2: softmax over S + c_s; 512 threads: 4 s-splits x 128 d.
// Writes cvec[dd*16 + b], dd 0..255 (h_t | c_s).
__global__ __launch_bounds__(512) void k_csum(
    const float* __restrict__ x, const float* __restrict__ scores,
    float* __restrict__ cvec)
{
  const int b = blockIdx.x;
  const int t = threadIdx.x;
  __shared__ float pr[S];
  __shared__ float redm[9];
  __shared__ float reds[9];
  __shared__ float cpart[3][D];

  float v = (t < S) ? scores[b * S + t] : -INFINITY;
  float m = v;
  #pragma unroll
  for (int off = 32; off > 0; off >>= 1) m = fmaxf(m, __shfl_down(m, off, 64));
  if ((t & 63) == 0) redm[t >> 6] = m;
  __syncthreads();
  if (t == 0) {
    float mm = redm[0];
    #pragma unroll
    for (int i = 1; i < 8; i++) mm = fmaxf(mm, redm[i]);
    redm[8] = mm;
  }
  __syncthreads();
  const float mx = redm[8];

  float e = (t < S) ? expf(v - mx) : 0.f;
  float s = e;
  #pragma unroll
  for (int off = 32; off > 0; off >>= 1) s += __shfl_down(s, off, 64);
  if ((t & 63) == 0) reds[t >> 6] = s;
  __syncthreads();
  if (t == 0) {
    float ss = 0.f;
    #pragma unroll
    for (int i = 0; i < 8; i++) ss += reds[i];
    reds[8] = ss;
  }
  __syncthreads();
  const float inv = 1.0f / reds[8];
  if (t < S) pr[t] = e * inv;
  __syncthreads();

  const int d = t & 127;
  const int sq = t >> 7;
  float acc = 0.f;
  const float* xb = x + ((size_t)b * S + sq * 50) * D + d;
  #pragma unroll 5
  for (int s2 = 0; s2 < 50; s2++) acc += pr[sq * 50 + s2] * xb[s2 * D];
  if (sq) cpart[sq - 1][d] = acc;
  __syncthreads();
  if (sq == 0) {
    cvec[d * B + b]       = x[(size_t)b * S * D + d];
    cvec[(D + d) * B + b] = acc + cpart[0][d] + cpart[1][d] + cpart[2][d];
  }
}

// K3: fused gemv + bias + exp + per-block partial sums.
// Structure: m97-style 2-phase global_load_lds double buffer.
//   - W tiles stream HBM -> LDS via __builtin_amdgcn_global_load_lds (width 16,
//     fire-and-forget DMA, no VGPR round trip, compiler-managed vmcnt drain at
//     __syncthreads -> structurally correct, unlike R8's hand-rolled waits).
//   - chunk = 32 d-rows x 256 v = 32 KB, double buffered; STAGE(next) issued
//     BEFORE compute(cur), so HBM latency hides under ~1024 cy of FMA.
//   - c-vector in LDS (broadcast ds_read, lgkmcnt path).
// Block: 256 threads; wave dq handles d in [dq*64, dq*64+64); lane owns one
// float4 column. Combine across the 4 d-quarters via LDS epilogue (reuses arena).
__global__ __launch_bounds__(256, 2) void k_gemv(
    const float* __restrict__ cvec, const float* __restrict__ Wec,
    const float* __restrict__ bec, float* __restrict__ out,
    float* __restrict__ partial)
{
  __shared__ __align__(16) char arena[81920];      // 64 KB wbuf + 16 KB c
  float (*wbuf)[32][VTILE] = (float (*)[32][VTILE])arena;   // [2][32][256]
  float* cl = (float*)(arena + 65536);                      // [256 d][16 b]

  const int t    = threadIdx.x;
  const int lane = t & 63;
  const int dq   = __builtin_amdgcn_readfirstlane(t >> 6);  // d-quarter

  // stage c once (coalesced float4)
  {
    const float4* src = (const float4*)cvec;
    float4* dst = (float4*)cl;
    #pragma unroll
    for (int i = 0; i < 4; i++) dst[t + 256 * i] = src[t + 256 * i];
  }

  const int vbase = blockIdx.x * VTILE;
  const int v4    = blockIdx.x * 64 + lane;    // this thread's float4 column
  const bool valid = (v4 < V4);
  const int v4c   = valid ? v4 : (V4 - 1);
  // per-lane source offset within a d-row (clamped for the tail block)
  const int laneoff = (vbase + lane * 4 + 3 < VOCAB) ? lane * 4 : 0;

#define STAGE(bufi, c)                                                      \
  { _Pragma("unroll")                                                       \
    for (int r = 0; r < 8; r++) {                                           \
      const int d = dq * 64 + (c) * 8 + r;                                  \
      const float* gp = Wec + (size_t)d * VOCAB + vbase + laneoff;          \
      float* lp = &wbuf[bufi][dq * 8 + r][0];                               \
      __builtin_amdgcn_global_load_lds(                                     \
          (const __attribute__((address_space(1))) void*)gp,                \
          (__attribute__((address_space(3))) void*)lp, 16, 0, 0);           \
    } }

  float4 acc[16];
  #pragma unroll
  for (int i = 0; i < 16; i++) acc[i] = make_float4(0.f, 0.f, 0.f, 0.f);

  STAGE(0, 0)
  __syncthreads();      // covers c-stage (lgkm) + chunk 0 DMA (vmcnt)

  int cur = 0;
  for (int c = 0; c < 8; c++) {
    if (c < 7) STAGE(cur ^ 1, c + 1)
    #pragma unroll
    for (int r = 0; r < 8; r++) {
      const float4 w = ((const float4*)&wbuf[cur][dq * 8 + r][0])[lane];
      const float* cj = cl + (dq * 64 + c * 8 + r) * 16;
      #pragma unroll
      for (int bb = 0; bb < 16; bb++) {
        const float cc = cj[bb];
        acc[bb].x = fmaf(w.x, cc, acc[bb].x);
        acc[bb].y = fmaf(w.y, cc, acc[bb].y);
        acc[bb].z = fmaf(w.z, cc, acc[bb].z);
        acc[bb].w = fmaf(w.w, cc, acc[bb].w);
      }
    }
    __syncthreads();    // drains next-chunk DMA + protects buffer reuse
    cur ^= 1;
  }
#undef STAGE

  // combine the 4 d-quarters via LDS (reuses arena; all wbuf reads done)
  float2* redp = (float2*)arena;
#define RED(q, l, b) redp[(((q) * 64 + (l)) * 17) + (b)]

  const float4 be4 = ((const float4*)bec)[v4c];
  float psum[4] = {0.f, 0.f, 0.f, 0.f};

  // Pass A: v-offsets 0,1 (acc .xy)
  #pragma unroll
  for (int bb = 0; bb < 16; bb++)
    RED(dq, lane, bb) = make_float2(acc[bb].x, acc[bb].y);
  __syncthreads();
  #pragma unroll
  for (int i = 0; i < 4; i++) {
    const int bb = dq * 4 + i;
    const float2 r0 = RED(0, lane, bb), r1 = RED(1, lane, bb);
    const float2 r2 = RED(2, lane, bb), r3 = RED(3, lane, bb);
    const float sx = r0.x + r1.x + r2.x + r3.x;
    const float sy = r0.y + r1.y + r2.y + r3.y;
    const float e0 = valid ? __expf(sx + be4.x) : 0.f;
    const float e1 = valid ? __expf(sy + be4.y) : 0.f;
    if (valid)
      *(float2*)&out[(size_t)bb * VOCAB + (size_t)v4 * 4] = make_float2(e0, e1);
    psum[i] += e0 + e1;
  }
  __syncthreads();

  // Pass B: v-offsets 2,3 (acc .zw)
  #pragma unroll
  for (int bb = 0; bb < 16; bb++)
    RED(dq, lane, bb) = make_float2(acc[bb].z, acc[bb].w);
  __syncthreads();
  #pragma unroll
  for (int i = 0; i < 4; i++) {
    const int bb = dq * 4 + i;
    const float2 r0 = RED(0, lane, bb), r1 = RED(1, lane, bb);
    const float2 r2 = RED(2, lane, bb), r3 = RED(3, lane, bb);
    const float sz = r0.x + r1.x + r2.x + r3.x;
    const float sw = r0.y + r1.y + r2.y + r3.y;
    const float e2 = valid ? __expf(sz + be4.z) : 0.f;
    const float e3 = valid ? __expf(sw + be4.w) : 0.f;
    if (valid)
      *(float2*)&out[(size_t)bb * VOCAB + (size_t)v4 * 4 + 2] = make_float2(e2, e3);
    psum[i] += e2 + e3;
  }
#undef RED

  #pragma unroll
  for (int i = 0; i < 4; i++) {
    float s = psum[i];
    #pragma unroll
    for (int off = 32; off > 0; off >>= 1) s += __shfl_down(s, off, 64);
    if (lane == 0) partial[blockIdx.x * 16 + dq * 4 + i] = s;
  }
}

// K4: single block: zero masked entries (duplicate-safe via atomicExch),
// subtract their exps from the sums, produce inv[b].
__global__ __launch_bounds__(256) void k_fix_inv(
    const int* __restrict__ ids, float* __restrict__ out,
    const float* __restrict__ partial, float* __restrict__ inv)
{
  const int t = threadIdx.x;
  __shared__ float corr[16];
  __shared__ float sred[256];

  if (t < 16) corr[t] = 0.f;
  __syncthreads();

  for (int i = t; i < B * S; i += 256) {
    const int id = ids[i];
    if (id > 1) {
      const int b = i / S;
      const float old = atomicExch(&out[(size_t)b * VOCAB + id], 0.f);
      atomicAdd(&corr[b], -old);
    }
  }

  float s = 0.f;
  #pragma unroll 4
  for (int j = (t >> 4); j < NBLK; j += 16) s += partial[j * 16 + (t & 15)];
  sred[t] = s;
  __syncthreads();

  if (t < 16) {
    float tot = 0.f;
    #pragma unroll
    for (int c = 0; c < 16; c++) tot += sred[c * 16 + t];
    inv[t] = 1.0f / (tot + corr[t]);
  }
}

// K5: scale in place, float4.
__global__ __launch_bounds__(256) void k_norm(float* __restrict__ out,
                                              const float* __restrict__ inv)
{
  const int b  = blockIdx.y;
  const int i4 = blockIdx.x * 256 + threadIdx.x;
  const float iv = inv[b];
  if (i4 < V4) {
    float4* p = (float4*)out + (size_t)b * V4 + i4;
    float4 q = *p;
    q.x *= iv; q.y *= iv; q.z *= iv; q.w *= iv;
    *p = q;
  }
}

extern "C" void kernel_launch(void* const* d_in, const int* in_sizes, int n_in,
                              void* d_out, int out_size, void* d_ws, size_t ws_size,
                              hipStream_t stream)
{
  const float* x   = (const float*)d_in[0];
  const int*   ids = (const int*)d_in[1];
  const float* Wq  = (const float*)d_in[2];
  const float* bq  = (const float*)d_in[3];
  const float* Wk  = (const float*)d_in[4];
  const float* bk  = (const float*)d_in[5];
  const float* Wv  = (const float*)d_in[6];
  const float* bv  = (const float*)d_in[7];
  const float* Wec = (const float*)d_in[8];
  const float* bec = (const float*)d_in[9];
  float* out = (float*)d_out;
  float* ws  = (float*)d_ws;

  float* scores  = ws;            // 3200
  float* cvec    = ws + 3200;     // 4096  ([256][16])
  float* partial = ws + 7296;     // NBLK*16 = 6256
  float* inv     = ws + 13552;    // 16

  k_scores <<<dim3(B * (S / SCH)), dim3(128), 0, stream>>>(x, Wq, bq, Wk, bk, Wv, bv, scores);
  k_csum   <<<dim3(B),             dim3(512), 0, stream>>>(x, scores, cvec);
  k_gemv   <<<dim3(NBLK),          dim3(256), 0, stream>>>(cvec, Wec, bec, out, partial);
  k_fix_inv<<<dim3(1),             dim3(256), 0, stream>>>(ids, out, partial, inv);
  k_norm   <<<dim3((V4 + 255) / 256, B), dim3(256), 0, stream>>>(out, inv);
}

// Round 10
// 66.418 us; speedup vs baseline: 1.1106x; 1.0035x over previous
//
#include <hip/hip_runtime.h>
#include <cstdint>
#include <cstddef>
#include <math.h>

#define B 16
#define S 200
#define D 128
#define VOCAB 100000
#define V4 (VOCAB / 4)                 // 25000 float4 columns
#define SCH 8
#define VTILE 256                      // vocab words per block
#define NBLK ((VOCAB + VTILE - 1) / VTILE)   // 391
#define CH 16                          // d-rows per chunk
#define NCH (2 * D / CH)               // 16 chunks

// K1: attention scores: per block = one (b, chunk of 8 s). 128 threads (one per e-dim).
__global__ __launch_bounds__(128) void k_scores(
    const float* __restrict__ x,
    const float* __restrict__ Wq, const float* __restrict__ bq,
    const float* __restrict__ Wk, const float* __restrict__ bk,
    const float* __restrict__ Wv, const float* __restrict__ bv,
    float* __restrict__ scores)
{
  const int b  = blockIdx.x / (S / SCH);
  const int s0 = (blockIdx.x % (S / SCH)) * SCH;
  const int e  = threadIdx.x;

  __shared__ float lx[SCH][D];
  __shared__ float l0[D];
  __shared__ float sred[2][SCH];

  l0[e] = x[(size_t)b * S * D + e];
  #pragma unroll
  for (int i = 0; i < SCH; i++) lx[i][e] = x[((size_t)b * S + s0 + i) * D + e];
  __syncthreads();

  float q[SCH];
  const float bqe = bq[e];
  #pragma unroll
  for (int i = 0; i < SCH; i++) q[i] = bqe;
  float kk = bk[e];

  for (int d = 0; d < D; d++) {
    const float wq = Wq[d * D + e];
    const float wk = Wk[d * D + e];
    const float x0 = l0[d];
    kk += x0 * wk;
    #pragma unroll
    for (int i = 0; i < SCH; i++) q[i] += lx[i][d] * wq;
  }

  const float wv  = Wv[e];
  const float bv0 = bv[0];
  #pragma unroll
  for (int i = 0; i < SCH; i++) {
    float val = tanhf(q[i] + kk) * wv;
    #pragma unroll
    for (int off = 32; off > 0; off >>= 1) val += __shfl_down(val, off, 64);
    if ((e & 63) == 0) sred[e >> 6][i] = val;
  }
  __syncthreads();
  if (e < SCH) scores[b * S + s0 + e] = sred[0][e] + sred[1][e] + bv0;
}

// K2: softmax over S + c_s; 512 threads: 4 s-splits x 128 d.
// Writes cvec[dd*16 + b], dd 0..255 (h_t | c_s).
__global__ __launch_bounds__(512) void k_csum(
    const float* __restrict__ x, const float* __restrict__ scores,
    float* __restrict__ cvec)
{
  const int b = blockIdx.x;
  const int t = threadIdx.x;
  __shared__ float pr[S];
  __shared__ float redm[9];
  __shared__ float reds[9];
  __shared__ float cpart[3][D];

  float v = (t < S) ? scores[b * S + t] : -INFINITY;
  float m = v;
  #pragma unroll
  for (int off = 32; off > 0; off >>= 1) m = fmaxf(m, __shfl_down(m, off, 64));
  if ((t & 63) == 0) redm[t >> 6] = m;
  __syncthreads();
  if (t == 0) {
    float mm = redm[0];
    #pragma unroll
    for (int i = 1; i < 8; i++) mm = fmaxf(mm, redm[i]);
    redm[8] = mm;
  }
  __syncthreads();
  const float mx = redm[8];

  float e = (t < S) ? expf(v - mx) : 0.f;
  float s = e;
  #pragma unroll
  for (int off = 32; off > 0; off >>= 1) s += __shfl_down(s, off, 64);
  if ((t & 63) == 0) reds[t >> 6] = s;
  __syncthreads();
  if (t == 0) {
    float ss = 0.f;
    #pragma unroll
    for (int i = 0; i < 8; i++) ss += reds[i];
    reds[8] = ss;
  }
  __syncthreads();
  const float inv = 1.0f / reds[8];
  if (t < S) pr[t] = e * inv;
  __syncthreads();

  const int d = t & 127;
  const int sq = t >> 7;
  float acc = 0.f;
  const float* xb = x + ((size_t)b * S + sq * 50) * D + d;
  #pragma unroll 5
  for (int s2 = 0; s2 < 50; s2++) acc += pr[sq * 50 + s2] * xb[s2 * D];
  if (sq) cpart[sq - 1][d] = acc;
  __syncthreads();
  if (sq == 0) {
    cvec[d * B + b]       = x[(size_t)b * S * D + d];
    cvec[(D + d) * B + b] = acc + cpart[0][d] + cpart[1][d] + cpart[2][d];
  }
}

// K3: fused gemv + bias + exp + per-block partial sums.
// Same 2-phase global_load_lds double-buffer as R9, but LDS arena shrunk
// 80 KB -> 48 KB (chunk 32 -> 16 d-rows): R9's 2x80 KB = exactly the 160 KB
// pool -- any runtime LDS reserve forces 1 block/CU and the 391-block grid
// runs in 2 serial rounds (~2x per-block time = the unexplained ~43 us).
// 48 KB guarantees 3 blocks/CU.
// Wave dq stages+computes rows {c*16 + dq*4 + r, r=0..3} of each chunk
// (64 d's per wave across 16 chunks); combine epilogue unchanged.
__global__ __launch_bounds__(256, 2) void k_gemv(
    const float* __restrict__ cvec, const float* __restrict__ Wec,
    const float* __restrict__ bec, float* __restrict__ out,
    float* __restrict__ partial)
{
  __shared__ __align__(16) char arena[49152];      // 32 KB wbuf + 16 KB c
  float (*wbuf)[CH][VTILE] = (float (*)[CH][VTILE])arena;   // [2][16][256]
  float* cl = (float*)(arena + 32768);                      // [256 d][16 b]

  const int t    = threadIdx.x;
  const int lane = t & 63;
  const int dq   = __builtin_amdgcn_readfirstlane(t >> 6);  // wave id

  // stage c once (coalesced float4)
  {
    const float4* src = (const float4*)cvec;
    float4* dst = (float4*)cl;
    #pragma unroll
    for (int i = 0; i < 4; i++) dst[t + 256 * i] = src[t + 256 * i];
  }

  const int vbase = blockIdx.x * VTILE;
  const int v4    = blockIdx.x * 64 + lane;    // this thread's float4 column
  const bool valid = (v4 < V4);
  const int v4c   = valid ? v4 : (V4 - 1);
  // per-lane source offset within a d-row (clamped for the tail block)
  const int laneoff = (vbase + lane * 4 + 3 < VOCAB) ? lane * 4 : 0;

#define STAGE(bufi, c)                                                      \
  { _Pragma("unroll")                                                       \
    for (int r = 0; r < 4; r++) {                                           \
      const int d = (c) * CH + dq * 4 + r;                                  \
      const float* gp = Wec + (size_t)d * VOCAB + vbase + laneoff;          \
      float* lp = &wbuf[bufi][dq * 4 + r][0];                               \
      __builtin_amdgcn_global_load_lds(                                     \
          (const __attribute__((address_space(1))) void*)gp,                \
          (__attribute__((address_space(3))) void*)lp, 16, 0, 0);           \
    } }

  float4 acc[16];
  #pragma unroll
  for (int i = 0; i < 16; i++) acc[i] = make_float4(0.f, 0.f, 0.f, 0.f);

  STAGE(0, 0)
  __syncthreads();      // covers c-stage (lgkm) + chunk 0 DMA (vmcnt)

  int cur = 0;
  for (int c = 0; c < NCH; c++) {
    if (c < NCH - 1) STAGE(cur ^ 1, c + 1)
    #pragma unroll
    for (int r = 0; r < 4; r++) {
      const float4 w = ((const float4*)&wbuf[cur][dq * 4 + r][0])[lane];
      const float* cj = cl + (c * CH + dq * 4 + r) * 16;
      #pragma unroll
      for (int bb = 0; bb < 16; bb++) {
        const float cc = cj[bb];
        acc[bb].x = fmaf(w.x, cc, acc[bb].x);
        acc[bb].y = fmaf(w.y, cc, acc[bb].y);
        acc[bb].z = fmaf(w.z, cc, acc[bb].z);
        acc[bb].w = fmaf(w.w, cc, acc[bb].w);
      }
    }
    __syncthreads();    // drains next-chunk DMA + protects buffer reuse
    cur ^= 1;
  }
#undef STAGE

  // combine the 4 waves' partial sums via LDS (reuses arena, 34816 B < 48 KB)
  float2* redp = (float2*)arena;
#define RED(q, l, b) redp[(((q) * 64 + (l)) * 17) + (b)]

  const float4 be4 = ((const float4*)bec)[v4c];
  float psum[4] = {0.f, 0.f, 0.f, 0.f};

  // Pass A: v-offsets 0,1 (acc .xy)
  #pragma unroll
  for (int bb = 0; bb < 16; bb++)
    RED(dq, lane, bb) = make_float2(acc[bb].x, acc[bb].y);
  __syncthreads();
  #pragma unroll
  for (int i = 0; i < 4; i++) {
    const int bb = dq * 4 + i;
    const float2 r0 = RED(0, lane, bb), r1 = RED(1, lane, bb);
    const float2 r2 = RED(2, lane, bb), r3 = RED(3, lane, bb);
    const float sx = r0.x + r1.x + r2.x + r3.x;
    const float sy = r0.y + r1.y + r2.y + r3.y;
    const float e0 = valid ? __expf(sx + be4.x) : 0.f;
    const float e1 = valid ? __expf(sy + be4.y) : 0.f;
    if (valid)
      *(float2*)&out[(size_t)bb * VOCAB + (size_t)v4 * 4] = make_float2(e0, e1);
    psum[i] += e0 + e1;
  }
  __syncthreads();

  // Pass B: v-offsets 2,3 (acc .zw)
  #pragma unroll
  for (int bb = 0; bb < 16; bb++)
    RED(dq, lane, bb) = make_float2(acc[bb].z, acc[bb].w);
  __syncthreads();
  #pragma unroll
  for (int i = 0; i < 4; i++) {
    const int bb = dq * 4 + i;
    const float2 r0 = RED(0, lane, bb), r1 = RED(1, lane, bb);
    const float2 r2 = RED(2, lane, bb), r3 = RED(3, lane, bb);
    const float sz = r0.x + r1.x + r2.x + r3.x;
    const float sw = r0.y + r1.y + r2.y + r3.y;
    const float e2 = valid ? __expf(sz + be4.z) : 0.f;
    const float e3 = valid ? __expf(sw + be4.w) : 0.f;
    if (valid)
      *(float2*)&out[(size_t)bb * VOCAB + (size_t)v4 * 4 + 2] = make_float2(e2, e3);
    psum[i] += e2 + e3;
  }
#undef RED

  #pragma unroll
  for (int i = 0; i < 4; i++) {
    float s = psum[i];
    #pragma unroll
    for (int off = 32; off > 0; off >>= 1) s += __shfl_down(s, off, 64);
    if (lane == 0) partial[blockIdx.x * 16 + dq * 4 + i] = s;
  }
}

// K4: single block: zero masked entries (duplicate-safe via atomicExch),
// subtract their exps from the sums, produce inv[b].
__global__ __launch_bounds__(256) void k_fix_inv(
    const int* __restrict__ ids, float* __restrict__ out,
    const float* __restrict__ partial, float* __restrict__ inv)
{
  const int t = threadIdx.x;
  __shared__ float corr[16];
  __shared__ float sred[256];

  if (t < 16) corr[t] = 0.f;
  __syncthreads();

  for (int i = t; i < B * S; i += 256) {
    const int id = ids[i];
    if (id > 1) {
      const int b = i / S;
      const float old = atomicExch(&out[(size_t)b * VOCAB + id], 0.f);
      atomicAdd(&corr[b], -old);
    }
  }

  float s = 0.f;
  #pragma unroll 4
  for (int j = (t >> 4); j < NBLK; j += 16) s += partial[j * 16 + (t & 15)];
  sred[t] = s;
  __syncthreads();

  if (t < 16) {
    float tot = 0.f;
    #pragma unroll
    for (int c = 0; c < 16; c++) tot += sred[c * 16 + t];
    inv[t] = 1.0f / (tot + corr[t]);
  }
}

// K5: scale in place, float4.
__global__ __launch_bounds__(256) void k_norm(float* __restrict__ out,
                                              const float* __restrict__ inv)
{
  const int b  = blockIdx.y;
  const int i4 = blockIdx.x * 256 + threadIdx.x;
  const float iv = inv[b];
  if (i4 < V4) {
    float4* p = (float4*)out + (size_t)b * V4 + i4;
    float4 q = *p;
    q.x *= iv; q.y *= iv; q.z *= iv; q.w *= iv;
    *p = q;
  }
}

extern "C" void kernel_launch(void* const* d_in, const int* in_sizes, int n_in,
                              void* d_out, int out_size, void* d_ws, size_t ws_size,
                              hipStream_t stream)
{
  const float* x   = (const float*)d_in[0];
  const int*   ids = (const int*)d_in[1];
  const float* Wq  = (const float*)d_in[2];
  const float* bq  = (const float*)d_in[3];
  const float* Wk  = (const float*)d_in[4];
  const float* bk  = (const float*)d_in[5];
  const float* Wv  = (const float*)d_in[6];
  const float* bv  = (const float*)d_in[7];
  const float* Wec = (const float*)d_in[8];
  const float* bec = (const float*)d_in[9];
  float* out = (float*)d_out;
  float* ws  = (float*)d_ws;

  float* scores  = ws;            // 3200
  float* cvec    = ws + 3200;     // 4096  ([256][16])
  float* partial = ws + 7296;     // NBLK*16 = 6256
  float* inv     = ws + 13552;    // 16

  k_scores <<<dim3(B * (S / SCH)), dim3(128), 0, stream>>>(x, Wq, bq, Wk, bk, Wv, bv, scores);
  k_csum   <<<dim3(B),             dim3(512), 0, stream>>>(x, scores, cvec);
  k_gemv   <<<dim3(NBLK),          dim3(256), 0, stream>>>(cvec, Wec, bec, out, partial);
  k_fix_inv<<<dim3(1),             dim3(256), 0, stream>>>(ids, out, partial, inv);
  k_norm   <<<dim3((V4 + 255) / 256, B), dim3(256), 0, stream>>>(out, inv);
}

// Round 11
// 57.267 us; speedup vs baseline: 1.2881x; 1.1598x over previous
//
#include <hip/hip_runtime.h>
#include <cstdint>
#include <cstddef>
#include <math.h>

#define B 16
#define S 200
#define D 128
#define VOCAB 100000
#define V4 (VOCAB / 4)                 // 25000 float4 columns
#define SCH 8
#define VTILE 256                      // vocab words per block
#define NBLK ((VOCAB + VTILE - 1) / VTILE)   // 391
#define CH 16                          // d-rows per chunk
#define NCH (2 * D / CH)               // 16 chunks

// K1: attention scores: per block = one (b, chunk of 8 s). 128 threads (one per e-dim).
__global__ __launch_bounds__(128) void k_scores(
    const float* __restrict__ x,
    const float* __restrict__ Wq, const float* __restrict__ bq,
    const float* __restrict__ Wk, const float* __restrict__ bk,
    const float* __restrict__ Wv, const float* __restrict__ bv,
    float* __restrict__ scores)
{
  const int b  = blockIdx.x / (S / SCH);
  const int s0 = (blockIdx.x % (S / SCH)) * SCH;
  const int e  = threadIdx.x;

  __shared__ float lx[SCH][D];
  __shared__ float l0[D];
  __shared__ float sred[2][SCH];

  l0[e] = x[(size_t)b * S * D + e];
  #pragma unroll
  for (int i = 0; i < SCH; i++) lx[i][e] = x[((size_t)b * S + s0 + i) * D + e];
  __syncthreads();

  float q[SCH];
  const float bqe = bq[e];
  #pragma unroll
  for (int i = 0; i < SCH; i++) q[i] = bqe;
  float kk = bk[e];

  for (int d = 0; d < D; d++) {
    const float wq = Wq[d * D + e];
    const float wk = Wk[d * D + e];
    const float x0 = l0[d];
    kk += x0 * wk;
    #pragma unroll
    for (int i = 0; i < SCH; i++) q[i] += lx[i][d] * wq;
  }

  const float wv  = Wv[e];
  const float bv0 = bv[0];
  #pragma unroll
  for (int i = 0; i < SCH; i++) {
    float val = tanhf(q[i] + kk) * wv;
    #pragma unroll
    for (int off = 32; off > 0; off >>= 1) val += __shfl_down(val, off, 64);
    if ((e & 63) == 0) sred[e >> 6][i] = val;
  }
  __syncthreads();
  if (e < SCH) scores[b * S + s0 + e] = sred[0][e] + sred[1][e] + bv0;
}

// K2: softmax over S + c_s; 512 threads: 4 s-splits x 128 d.
// Writes cvec[dd*16 + b], dd 0..255 (h_t | c_s).
__global__ __launch_bounds__(512) void k_csum(
    const float* __restrict__ x, const float* __restrict__ scores,
    float* __restrict__ cvec)
{
  const int b = blockIdx.x;
  const int t = threadIdx.x;
  __shared__ float pr[S];
  __shared__ float redm[9];
  __shared__ float reds[9];
  __shared__ float cpart[3][D];

  float v = (t < S) ? scores[b * S + t] : -INFINITY;
  float m = v;
  #pragma unroll
  for (int off = 32; off > 0; off >>= 1) m = fmaxf(m, __shfl_down(m, off, 64));
  if ((t & 63) == 0) redm[t >> 6] = m;
  __syncthreads();
  if (t == 0) {
    float mm = redm[0];
    #pragma unroll
    for (int i = 1; i < 8; i++) mm = fmaxf(mm, redm[i]);
    redm[8] = mm;
  }
  __syncthreads();
  const float mx = redm[8];

  float e = (t < S) ? expf(v - mx) : 0.f;
  float s = e;
  #pragma unroll
  for (int off = 32; off > 0; off >>= 1) s += __shfl_down(s, off, 64);
  if ((t & 63) == 0) reds[t >> 6] = s;
  __syncthreads();
  if (t == 0) {
    float ss = 0.f;
    #pragma unroll
    for (int i = 0; i < 8; i++) ss += reds[i];
    reds[8] = ss;
  }
  __syncthreads();
  const float inv = 1.0f / reds[8];
  if (t < S) pr[t] = e * inv;
  __syncthreads();

  const int d = t & 127;
  const int sq = t >> 7;
  float acc = 0.f;
  const float* xb = x + ((size_t)b * S + sq * 50) * D + d;
  #pragma unroll 5
  for (int s2 = 0; s2 < 50; s2++) acc += pr[sq * 50 + s2] * xb[s2 * D];
  if (sq) cpart[sq - 1][d] = acc;
  __syncthreads();
  if (sq == 0) {
    cvec[d * B + b]       = x[(size_t)b * S * D + d];
    cvec[(D + d) * B + b] = acc + cpart[0][d] + cpart[1][d] + cpart[2][d];
  }
}

// K3: fused gemv + bias + mask + exp + per-block partial sums.
// Same 2-phase global_load_lds double-buffer as R10, PLUS an LDS bitmap of
// masked vocab ids in this block's 256-v range (expected ~8 hits): masked
// entries write exp=0 and drop out of psum -- exactly exp(-inf), duplicate
// safe. This removes the serial-atomic k_fix_inv kernel entirely.
__global__ __launch_bounds__(256, 2) void k_gemv(
    const float* __restrict__ cvec, const float* __restrict__ Wec,
    const float* __restrict__ bec, const int* __restrict__ ids,
    float* __restrict__ out, float* __restrict__ partial)
{
  __shared__ __align__(16) char arena[49152];      // 32 KB wbuf + 16 KB c
  float (*wbuf)[CH][VTILE] = (float (*)[CH][VTILE])arena;   // [2][16][256]
  float* cl = (float*)(arena + 32768);                      // [256 d][16 b]
  __shared__ unsigned mbit[B * 8];                 // 16 b x 256 v bits

  const int t    = threadIdx.x;
  const int lane = t & 63;
  const int dq   = __builtin_amdgcn_readfirstlane(t >> 6);  // wave id

  // stage c once (coalesced float4)
  {
    const float4* src = (const float4*)cvec;
    float4* dst = (float4*)cl;
    #pragma unroll
    for (int i = 0; i < 4; i++) dst[t + 256 * i] = src[t + 256 * i];
  }
  if (t < B * 8) mbit[t] = 0u;

  const int vbase = blockIdx.x * VTILE;
  const int v4    = blockIdx.x * 64 + lane;    // this thread's float4 column
  const bool valid = (v4 < V4);
  const int v4c   = valid ? v4 : (V4 - 1);
  // per-lane source offset within a d-row (clamped for the tail block)
  const int laneoff = (vbase + lane * 4 + 3 < VOCAB) ? lane * 4 : 0;

#define STAGE(bufi, c)                                                      \
  { _Pragma("unroll")                                                       \
    for (int r = 0; r < 4; r++) {                                           \
      const int d = (c) * CH + dq * 4 + r;                                  \
      const float* gp = Wec + (size_t)d * VOCAB + vbase + laneoff;          \
      float* lp = &wbuf[bufi][dq * 4 + r][0];                               \
      __builtin_amdgcn_global_load_lds(                                     \
          (const __attribute__((address_space(1))) void*)gp,                \
          (__attribute__((address_space(3))) void*)lp, 16, 0, 0);           \
    } }

  float4 acc[16];
  #pragma unroll
  for (int i = 0; i < 16; i++) acc[i] = make_float4(0.f, 0.f, 0.f, 0.f);

  STAGE(0, 0)

  // build mask bitmap for this block's v-range (overlaps with chunk-0 DMA)
  for (int i = t; i < B * S; i += 256) {
    const int id = ids[i];
    if (id > 1 && id >= vbase && id < vbase + VTILE) {
      const int lv = id - vbase;
      atomicOr(&mbit[(i / S) * 8 + (lv >> 5)], 1u << (lv & 31));
    }
  }

  __syncthreads();      // covers c-stage + bitmap (lgkm) + chunk 0 DMA (vmcnt)

  int cur = 0;
  for (int c = 0; c < NCH; c++) {
    if (c < NCH - 1) STAGE(cur ^ 1, c + 1)
    #pragma unroll
    for (int r = 0; r < 4; r++) {
      const float4 w = ((const float4*)&wbuf[cur][dq * 4 + r][0])[lane];
      const float* cj = cl + (c * CH + dq * 4 + r) * 16;
      #pragma unroll
      for (int bb = 0; bb < 16; bb++) {
        const float cc = cj[bb];
        acc[bb].x = fmaf(w.x, cc, acc[bb].x);
        acc[bb].y = fmaf(w.y, cc, acc[bb].y);
        acc[bb].z = fmaf(w.z, cc, acc[bb].z);
        acc[bb].w = fmaf(w.w, cc, acc[bb].w);
      }
    }
    __syncthreads();    // drains next-chunk DMA + protects buffer reuse
    cur ^= 1;
  }
#undef STAGE

  // combine the 4 waves' partial sums via LDS (reuses arena, 34816 B < 48 KB)
  float2* redp = (float2*)arena;
#define RED(q, l, b) redp[(((q) * 64 + (l)) * 17) + (b)]
#define MASKED(bb, lv) ((mbit[(bb) * 8 + ((lv) >> 5)] >> ((lv) & 31)) & 1u)

  const float4 be4 = ((const float4*)bec)[v4c];
  const int lv0 = lane * 4;
  float psum[4] = {0.f, 0.f, 0.f, 0.f};

  // Pass A: v-offsets 0,1 (acc .xy)
  #pragma unroll
  for (int bb = 0; bb < 16; bb++)
    RED(dq, lane, bb) = make_float2(acc[bb].x, acc[bb].y);
  __syncthreads();
  #pragma unroll
  for (int i = 0; i < 4; i++) {
    const int bb = dq * 4 + i;
    const float2 r0 = RED(0, lane, bb), r1 = RED(1, lane, bb);
    const float2 r2 = RED(2, lane, bb), r3 = RED(3, lane, bb);
    const float sx = r0.x + r1.x + r2.x + r3.x;
    const float sy = r0.y + r1.y + r2.y + r3.y;
    float e0 = 0.f, e1 = 0.f;
    if (valid) {
      e0 = MASKED(bb, lv0 + 0) ? 0.f : __expf(sx + be4.x);
      e1 = MASKED(bb, lv0 + 1) ? 0.f : __expf(sy + be4.y);
      *(float2*)&out[(size_t)bb * VOCAB + (size_t)v4 * 4] = make_float2(e0, e1);
    }
    psum[i] += e0 + e1;
  }
  __syncthreads();

  // Pass B: v-offsets 2,3 (acc .zw)
  #pragma unroll
  for (int bb = 0; bb < 16; bb++)
    RED(dq, lane, bb) = make_float2(acc[bb].z, acc[bb].w);
  __syncthreads();
  #pragma unroll
  for (int i = 0; i < 4; i++) {
    const int bb = dq * 4 + i;
    const float2 r0 = RED(0, lane, bb), r1 = RED(1, lane, bb);
    const float2 r2 = RED(2, lane, bb), r3 = RED(3, lane, bb);
    const float sz = r0.x + r1.x + r2.x + r3.x;
    const float sw = r0.y + r1.y + r2.y + r3.y;
    float e2 = 0.f, e3 = 0.f;
    if (valid) {
      e2 = MASKED(bb, lv0 + 2) ? 0.f : __expf(sz + be4.z);
      e3 = MASKED(bb, lv0 + 3) ? 0.f : __expf(sw + be4.w);
      *(float2*)&out[(size_t)bb * VOCAB + (size_t)v4 * 4 + 2] = make_float2(e2, e3);
    }
    psum[i] += e2 + e3;
  }
#undef RED
#undef MASKED

  #pragma unroll
  for (int i = 0; i < 4; i++) {
    float s = psum[i];
    #pragma unroll
    for (int off = 32; off > 0; off >>= 1) s += __shfl_down(s, off, 64);
    if (lane == 0) partial[blockIdx.x * 16 + dq * 4 + i] = s;
  }
}

// K4: normalize; each block reduces the 391 partials for its batch inline
// (1.6 KB redundant read per block, fully parallel), then scales float4.
__global__ __launch_bounds__(256) void k_norm(float* __restrict__ out,
                                              const float* __restrict__ partial)
{
  const int b  = blockIdx.y;
  const int t  = threadIdx.x;
  __shared__ float red[4];

  float s = 0.f;
  for (int j = t; j < NBLK; j += 256) s += partial[j * 16 + b];
  #pragma unroll
  for (int off = 32; off > 0; off >>= 1) s += __shfl_down(s, off, 64);
  if ((t & 63) == 0) red[t >> 6] = s;
  __syncthreads();
  const float iv = 1.0f / (red[0] + red[1] + red[2] + red[3]);

  const int i4 = blockIdx.x * 256 + t;
  if (i4 < V4) {
    float4* p = (float4*)out + (size_t)b * V4 + i4;
    float4 q = *p;
    q.x *= iv; q.y *= iv; q.z *= iv; q.w *= iv;
    *p = q;
  }
}

extern "C" void kernel_launch(void* const* d_in, const int* in_sizes, int n_in,
                              void* d_out, int out_size, void* d_ws, size_t ws_size,
                              hipStream_t stream)
{
  const float* x   = (const float*)d_in[0];
  const int*   ids = (const int*)d_in[1];
  const float* Wq  = (const float*)d_in[2];
  const float* bq  = (const float*)d_in[3];
  const float* Wk  = (const float*)d_in[4];
  const float* bk  = (const float*)d_in[5];
  const float* Wv  = (const float*)d_in[6];
  const float* bv  = (const float*)d_in[7];
  const float* Wec = (const float*)d_in[8];
  const float* bec = (const float*)d_in[9];
  float* out = (float*)d_out;
  float* ws  = (float*)d_ws;

  float* scores  = ws;            // 3200
  float* cvec    = ws + 3200;     // 4096  ([256][16])
  float* partial = ws + 7296;     // NBLK*16 = 6256

  k_scores <<<dim3(B * (S / SCH)), dim3(128), 0, stream>>>(x, Wq, bq, Wk, bk, Wv, bv, scores);
  k_csum   <<<dim3(B),             dim3(512), 0, stream>>>(x, scores, cvec);
  k_gemv   <<<dim3(NBLK),          dim3(256), 0, stream>>>(cvec, Wec, bec, ids, out, partial);
  k_norm   <<<dim3((V4 + 255) / 256, B), dim3(256), 0, stream>>>(out, partial);
}